// Round 1
// baseline (761.637 us; speedup 1.0000x reference)
//
#include <hip/hip_runtime.h>

#define D 128
#define HID 128
#define HEADS 4
#define OUTD 64

static __device__ __forceinline__ float leaky(float v) { return v > 0.f ? v : 0.2f * v; }

static __device__ __forceinline__ float wred_max(float v) {
    #pragma unroll
    for (int o = 32; o; o >>= 1) v = fmaxf(v, __shfl_xor(v, o));
    return v;
}
static __device__ __forceinline__ float wred_sum(float v) {
    #pragma unroll
    for (int o = 32; o; o >>= 1) v += __shfl_xor(v, o);
    return v;
}

// ---------------- CSR build ----------------
__global__ void k_count(const int* __restrict__ ei, int E, int* __restrict__ deg) {
    int i = blockIdx.x * 256 + threadIdx.x;
    if (i < E) atomicAdd(&deg[ei[E + i]], 1);
}

__global__ void k_scan_local(const int* __restrict__ deg, int N,
                             int* __restrict__ rowptr, int* __restrict__ bsum) {
    __shared__ int s[256];
    int t = threadIdx.x;
    int i = blockIdx.x * 256 + t;
    int v = (i < N) ? deg[i] : 0;
    s[t] = v;
    __syncthreads();
    for (int off = 1; off < 256; off <<= 1) {
        int tv = (t >= off) ? s[t - off] : 0;
        __syncthreads();
        s[t] += tv;
        __syncthreads();
    }
    rowptr[i] = s[t] - v;  // exclusive
    if (t == 255) bsum[blockIdx.x] = s[255];
}

__global__ void k_scan_bsum(const int* __restrict__ bsum, int nb, int* __restrict__ bexc) {
    __shared__ int s[256];
    int t = threadIdx.x;
    int v = (t < nb) ? bsum[t] : 0;
    s[t] = v;
    __syncthreads();
    for (int off = 1; off < 256; off <<= 1) {
        int tv = (t >= off) ? s[t - off] : 0;
        __syncthreads();
        s[t] += tv;
        __syncthreads();
    }
    bexc[t] = s[t] - v;
}

__global__ void k_scan_add(int* __restrict__ rowptr, const int* __restrict__ bexc) {
    int i = blockIdx.x * 256 + threadIdx.x;
    rowptr[i] += bexc[blockIdx.x];
}

__global__ void k_scatter(const int* __restrict__ ei, int E, const int* __restrict__ rowptr,
                          int* __restrict__ fill, int* __restrict__ csr) {
    int i = blockIdx.x * 256 + threadIdx.x;
    if (i < E) {
        int d = ei[E + i];
        int pos = rowptr[d] + atomicAdd(&fill[d], 1);
        csr[pos] = ei[i];
    }
}

// ---------------- SAGE mean aggregation: wave per node ----------------
__global__ __launch_bounds__(256) void k_sage_mean(const int* __restrict__ rowptr,
                                                   const int* __restrict__ csr,
                                                   const float* __restrict__ x,
                                                   float* __restrict__ mean, int N) {
    int n = blockIdx.x * 4 + (threadIdx.x >> 6);
    if (n >= N) return;
    int lane = threadIdx.x & 63;
    int e0 = rowptr[n], e1 = rowptr[n + 1];
    float ax = 0.f, ay = 0.f;
    for (int e = e0; e < e1; e++) {
        int s = csr[e];
        float2 v = *(const float2*)(x + (size_t)s * D + lane * 2);
        ax += v.x; ay += v.y;
    }
    int dg = e1 - e0;
    float inv = 1.0f / (float)(dg > 0 ? dg : 1);
    float2 o; o.x = ax * inv; o.y = ay * inv;
    *(float2*)(mean + (size_t)n * D + lane * 2) = o;
}

// ---------------- h = relu(mean @ W_l + x @ W_r + b_sage) ----------------
__global__ __launch_bounds__(256) void k_gemm_h(const float* __restrict__ mean,
                                                const float* __restrict__ x,
                                                const float* __restrict__ Wl,
                                                const float* __restrict__ Wr,
                                                const float* __restrict__ bias,
                                                float* __restrict__ h, int N) {
    __shared__ float sA[32][128];
    __shared__ float sX[32][128];
    int n0 = blockIdx.x * 32;
    int tid = threadIdx.x;
    for (int i = tid * 4; i < 32 * 128; i += 1024) {
        int r = i >> 7, c = i & 127;
        float4 a = {0, 0, 0, 0}, xx = {0, 0, 0, 0};
        if (n0 + r < N) {
            a = *(const float4*)(mean + (size_t)(n0 + r) * 128 + c);
            xx = *(const float4*)(x + (size_t)(n0 + r) * 128 + c);
        }
        *(float4*)&sA[r][c] = a;
        *(float4*)&sX[r][c] = xx;
    }
    __syncthreads();
    int j0 = (tid & 31) * 4;
    int m0 = (tid >> 5) * 4;
    float acc[4][4] = {};
    #pragma unroll 4
    for (int k = 0; k < 128; k++) {
        float4 w1 = *(const float4*)(Wl + k * 128 + j0);
        float4 w2 = *(const float4*)(Wr + k * 128 + j0);
        #pragma unroll
        for (int m = 0; m < 4; m++) {
            float a = sA[m0 + m][k], b = sX[m0 + m][k];
            acc[m][0] += a * w1.x + b * w2.x;
            acc[m][1] += a * w1.y + b * w2.y;
            acc[m][2] += a * w1.z + b * w2.z;
            acc[m][3] += a * w1.w + b * w2.w;
        }
    }
    float4 bb = *(const float4*)(bias + j0);
    #pragma unroll
    for (int m = 0; m < 4; m++) {
        int n = n0 + m0 + m;
        if (n < N) {
            float4 o;
            o.x = fmaxf(acc[m][0] + bb.x, 0.f);
            o.y = fmaxf(acc[m][1] + bb.y, 0.f);
            o.z = fmaxf(acc[m][2] + bb.z, 0.f);
            o.w = fmaxf(acc[m][3] + bb.w, 0.f);
            *(float4*)(h + (size_t)n * 128 + j0) = o;
        }
    }
}

// ---------------- wsd[k][o] : o<4 -> src att-vec, o>=4 -> dst att-vec ----------------
__global__ void k_wsd(const float* __restrict__ Ws, const float* __restrict__ Wd,
                      const float* __restrict__ atts, const float* __restrict__ attd,
                      float* __restrict__ wsd) {
    int t = blockIdx.x * 256 + threadIdx.x;
    if (t >= 1024) return;
    int k = t >> 3, o = t & 7;
    int hh = o & 3;
    const float* W = (o < 4) ? Ws : Wd;
    const float* att = (o < 4) ? atts : attd;
    float acc = 0.f;
    for (int c = 0; c < 128; c++) acc += W[k * 512 + hh * 128 + c] * att[hh * 128 + c];
    wsd[k * 8 + o] = acc;
}

// ---------------- a_s[N,4], a_d[N,4] = h @ wsd ----------------
__global__ __launch_bounds__(256) void k_asd(const float* __restrict__ h,
                                             const float* __restrict__ wsd,
                                             float* __restrict__ a_s, float* __restrict__ a_d, int N) {
    __shared__ float sH[32][128];
    int n0 = blockIdx.x * 32;
    int tid = threadIdx.x;
    for (int i = tid * 4; i < 32 * 128; i += 1024) {
        int r = i >> 7, c = i & 127;
        float4 v = {0, 0, 0, 0};
        if (n0 + r < N) v = *(const float4*)(h + (size_t)(n0 + r) * 128 + c);
        *(float4*)&sH[r][c] = v;
    }
    __syncthreads();
    int m = tid >> 3, o = tid & 7;
    float acc = 0.f;
    #pragma unroll 4
    for (int k = 0; k < 128; k++) acc += sH[m][k] * wsd[k * 8 + o];
    int n = n0 + m;
    if (n < N) {
        if (o < 4) a_s[n * 4 + o] = acc;
        else       a_d[n * 4 + (o - 4)] = acc;
    }
}

// ---------------- hs = h @ W_src  ([N,128]@[128,512]) ----------------
__global__ __launch_bounds__(256) void k_gemm_hs(const float* __restrict__ h,
                                                 const float* __restrict__ Ws,
                                                 float* __restrict__ hs, int N) {
    __shared__ float sH[32][128];
    int n0 = blockIdx.x * 32;
    int jb = blockIdx.y * 128;
    int tid = threadIdx.x;
    for (int i = tid * 4; i < 32 * 128; i += 1024) {
        int r = i >> 7, c = i & 127;
        float4 v = {0, 0, 0, 0};
        if (n0 + r < N) v = *(const float4*)(h + (size_t)(n0 + r) * 128 + c);
        *(float4*)&sH[r][c] = v;
    }
    __syncthreads();
    int j0 = (tid & 31) * 4;
    int m0 = (tid >> 5) * 4;
    float acc[4][4] = {};
    #pragma unroll 4
    for (int k = 0; k < 128; k++) {
        float4 w = *(const float4*)(Ws + k * 512 + jb + j0);
        #pragma unroll
        for (int m = 0; m < 4; m++) {
            float a = sH[m0 + m][k];
            acc[m][0] += a * w.x;
            acc[m][1] += a * w.y;
            acc[m][2] += a * w.z;
            acc[m][3] += a * w.w;
        }
    }
    #pragma unroll
    for (int m = 0; m < 4; m++) {
        int n = n0 + m0 + m;
        if (n < N) {
            float4 o;
            o.x = acc[m][0]; o.y = acc[m][1]; o.z = acc[m][2]; o.w = acc[m][3];
            *(float4*)(hs + (size_t)n * 512 + jb + j0) = o;
        }
    }
}

// ---------------- GAT: edge softmax + weighted aggregation, wave per node ----------------
__global__ __launch_bounds__(256) void k_gat(const int* __restrict__ rowptr,
                                             const int* __restrict__ csr,
                                             const float* __restrict__ hs,
                                             const float* __restrict__ a_s,
                                             const float* __restrict__ a_d,
                                             float* __restrict__ outm, int N) {
    int n = blockIdx.x * 4 + (threadIdx.x >> 6);
    if (n >= N) return;
    int lane = threadIdx.x & 63;
    int e0 = rowptr[n], e1 = rowptr[n + 1];
    float4 ad = *(const float4*)(a_d + (size_t)n * 4);

    // pass 1: per-head max over incoming edges
    float mx0 = -1e30f, mx1 = -1e30f, mx2 = -1e30f, mx3 = -1e30f;
    for (int base = e0; base < e1; base += 64) {
        int e = base + lane;
        if (e < e1) {
            int s = csr[e];
            float4 as = *(const float4*)(a_s + (size_t)s * 4);
            mx0 = fmaxf(mx0, leaky(as.x + ad.x));
            mx1 = fmaxf(mx1, leaky(as.y + ad.y));
            mx2 = fmaxf(mx2, leaky(as.z + ad.z));
            mx3 = fmaxf(mx3, leaky(as.w + ad.w));
        }
    }
    mx0 = wred_max(mx0); mx1 = wred_max(mx1); mx2 = wred_max(mx2); mx3 = wred_max(mx3);

    // pass 2: denominators
    float s0 = 0.f, s1 = 0.f, s2 = 0.f, s3 = 0.f;
    for (int base = e0; base < e1; base += 64) {
        int e = base + lane;
        if (e < e1) {
            int s = csr[e];
            float4 as = *(const float4*)(a_s + (size_t)s * 4);
            s0 += __expf(leaky(as.x + ad.x) - mx0);
            s1 += __expf(leaky(as.y + ad.y) - mx1);
            s2 += __expf(leaky(as.z + ad.z) - mx2);
            s3 += __expf(leaky(as.w + ad.w) - mx3);
        }
    }
    s0 = wred_sum(s0); s1 = wred_sum(s1); s2 = wred_sum(s2); s3 = wred_sum(s3);
    float i0 = s0 > 0.f ? 1.f / s0 : 0.f;
    float i1 = s1 > 0.f ? 1.f / s1 : 0.f;
    float i2 = s2 > 0.f ? 1.f / s2 : 0.f;
    float i3 = s3 > 0.f ? 1.f / s3 : 0.f;

    // pass 3: weighted aggregation, heads fused, mean folded in
    float accx = 0.f, accy = 0.f;
    for (int e = e0; e < e1; e++) {
        int s = csr[e];  // uniform across wave
        float4 as = *(const float4*)(a_s + (size_t)s * 4);
        float al0 = __expf(leaky(as.x + ad.x) - mx0) * i0;
        float al1 = __expf(leaky(as.y + ad.y) - mx1) * i1;
        float al2 = __expf(leaky(as.z + ad.z) - mx2) * i2;
        float al3 = __expf(leaky(as.w + ad.w) - mx3) * i3;
        const float2* hp = (const float2*)(hs + (size_t)s * 512);
        float2 v0 = hp[lane];
        float2 v1 = hp[64 + lane];
        float2 v2 = hp[128 + lane];
        float2 v3 = hp[192 + lane];
        accx += al0 * v0.x + al1 * v1.x + al2 * v2.x + al3 * v3.x;
        accy += al0 * v0.y + al1 * v1.y + al2 * v2.y + al3 * v3.y;
    }
    float2 o; o.x = accx * 0.25f; o.y = accy * 0.25f;
    *(float2*)(outm + (size_t)n * 128 + lane * 2) = o;
}

// ---------------- out = relu(outm + b_gat) @ W_lin + b_lin ----------------
__global__ __launch_bounds__(256) void k_final(const float* __restrict__ outm,
                                               const float* __restrict__ bg,
                                               const float* __restrict__ Wlin,
                                               const float* __restrict__ bl,
                                               float* __restrict__ out, int N) {
    __shared__ float sA[64][128];
    int n0 = blockIdx.x * 64;
    int tid = threadIdx.x;
    for (int i = tid * 4; i < 64 * 128; i += 1024) {
        int r = i >> 7, c = i & 127;
        float4 v = {0, 0, 0, 0};
        if (n0 + r < N) {
            float4 t = *(const float4*)(outm + (size_t)(n0 + r) * 128 + c);
            float4 b = *(const float4*)(bg + c);
            v.x = fmaxf(t.x + b.x, 0.f);
            v.y = fmaxf(t.y + b.y, 0.f);
            v.z = fmaxf(t.z + b.z, 0.f);
            v.w = fmaxf(t.w + b.w, 0.f);
        }
        *(float4*)&sA[r][c] = v;
    }
    __syncthreads();
    int j0 = (tid & 15) * 4;
    int m0 = (tid >> 4) * 4;
    float acc[4][4] = {};
    #pragma unroll 4
    for (int k = 0; k < 128; k++) {
        float4 w = *(const float4*)(Wlin + k * 64 + j0);
        #pragma unroll
        for (int m = 0; m < 4; m++) {
            float a = sA[m0 + m][k];
            acc[m][0] += a * w.x;
            acc[m][1] += a * w.y;
            acc[m][2] += a * w.z;
            acc[m][3] += a * w.w;
        }
    }
    float4 bb = *(const float4*)(bl + j0);
    #pragma unroll
    for (int m = 0; m < 4; m++) {
        int n = n0 + m0 + m;
        if (n < N) {
            float4 o;
            o.x = acc[m][0] + bb.x;
            o.y = acc[m][1] + bb.y;
            o.z = acc[m][2] + bb.z;
            o.w = acc[m][3] + bb.w;
            *(float4*)(out + (size_t)n * 64 + j0) = o;
        }
    }
}

extern "C" void kernel_launch(void* const* d_in, const int* in_sizes, int n_in,
                              void* d_out, int out_size, void* d_ws, size_t ws_size,
                              hipStream_t stream) {
    const float* x    = (const float*)d_in[0];
    const int*   ei   = (const int*)d_in[1];
    const float* Wl   = (const float*)d_in[2];
    const float* Wr   = (const float*)d_in[3];
    const float* bs   = (const float*)d_in[4];
    const float* Wsrc = (const float*)d_in[5];
    const float* Wdst = (const float*)d_in[6];
    const float* atts = (const float*)d_in[7];
    const float* attd = (const float*)d_in[8];
    const float* bg   = (const float*)d_in[9];
    const float* Wlin = (const float*)d_in[10];
    const float* bl   = (const float*)d_in[11];
    int N = in_sizes[0] / D;
    int E = in_sizes[1] / 2;

    char* w = (char*)d_ws;
    auto alloc = [&](size_t bytes) {
        char* p = w;
        w += (bytes + 255) & ~(size_t)255;
        return p;
    };
    float* mean  = (float*)alloc((size_t)N * 128 * 4);   // reused as outm after gemm_h
    float* hbuf  = (float*)alloc((size_t)N * 128 * 4);
    float* hsb   = (float*)alloc((size_t)N * 512 * 4);
    float* a_s   = (float*)alloc((size_t)N * 4 * 4);
    float* a_d   = (float*)alloc((size_t)N * 4 * 4);
    float* wsd   = (float*)alloc(1024 * 4);
    int* rowptr  = (int*)alloc((size_t)(N + 512) * 4);
    int* deg     = (int*)alloc((size_t)N * 4);
    int* fill    = (int*)alloc((size_t)N * 4);
    int* bsum    = (int*)alloc(256 * 4);
    int* bexc    = (int*)alloc(256 * 4);
    int* csr     = (int*)alloc((size_t)E * 4);
    (void)ws_size; (void)n_in; (void)out_size;

    hipMemsetAsync(deg, 0, (size_t)N * 4, stream);
    hipMemsetAsync(fill, 0, (size_t)N * 4, stream);

    int nb = (N + 255) / 256;
    k_count<<<(E + 255) / 256, 256, 0, stream>>>(ei, E, deg);
    k_scan_local<<<nb, 256, 0, stream>>>(deg, N, rowptr, bsum);
    k_scan_bsum<<<1, 256, 0, stream>>>(bsum, nb, bexc);
    k_scan_add<<<nb, 256, 0, stream>>>(rowptr, bexc);
    k_scatter<<<(E + 255) / 256, 256, 0, stream>>>(ei, E, rowptr, fill, csr);

    k_sage_mean<<<(N + 3) / 4, 256, 0, stream>>>(rowptr, csr, x, mean, N);
    k_gemm_h<<<(N + 31) / 32, 256, 0, stream>>>(mean, x, Wl, Wr, bs, hbuf, N);
    k_wsd<<<4, 256, 0, stream>>>(Wsrc, Wdst, atts, attd, wsd);
    k_asd<<<(N + 31) / 32, 256, 0, stream>>>(hbuf, wsd, a_s, a_d, N);
    dim3 ghs((N + 31) / 32, 4);
    k_gemm_hs<<<ghs, 256, 0, stream>>>(hbuf, Wsrc, hsb, N);
    k_gat<<<(N + 3) / 4, 256, 0, stream>>>(rowptr, csr, hsb, a_s, a_d, mean, N);
    k_final<<<(N + 63) / 64, 256, 0, stream>>>(mean, bg, Wlin, bl, (float*)d_out, N);
}

// Round 3
// 564.243 us; speedup vs baseline: 1.3498x; 1.3498x over previous
//
#include <hip/hip_runtime.h>

#define D 128
#define HID 128
#define HEADS 4
#define OUTD 64

static __device__ __forceinline__ float leaky(float v) { return v > 0.f ? v : 0.2f * v; }

static __device__ __forceinline__ float2 bf2_to_f2(unsigned int u) {
    float2 r;
    union { unsigned int i; float f; } a, b;
    a.i = (u & 0xffffu) << 16;
    b.i = u & 0xffff0000u;
    r.x = a.f; r.y = b.f;
    return r;
}
static __device__ __forceinline__ unsigned short f2bf(float f) {
    union { float f; unsigned int i; } v; v.f = f;
    unsigned int u = v.i;
    unsigned int r = (u + 0x7fffu + ((u >> 16) & 1u)) >> 16;
    return (unsigned short)r;
}

// ---------------- CSR build ----------------
__global__ void k_count(const int* __restrict__ ei, int E, int* __restrict__ deg) {
    int i = blockIdx.x * 256 + threadIdx.x;
    if (i < E) atomicAdd(&deg[ei[E + i]], 1);
}

__global__ void k_scan_local(const int* __restrict__ deg, int N,
                             int* __restrict__ rowptr, int* __restrict__ bsum) {
    __shared__ int s[256];
    int t = threadIdx.x;
    int i = blockIdx.x * 256 + t;
    int v = (i < N) ? deg[i] : 0;
    s[t] = v;
    __syncthreads();
    for (int off = 1; off < 256; off <<= 1) {
        int tv = (t >= off) ? s[t - off] : 0;
        __syncthreads();
        s[t] += tv;
        __syncthreads();
    }
    rowptr[i] = s[t] - v;  // exclusive
    if (t == 255) bsum[blockIdx.x] = s[255];
}

__global__ void k_scan_bsum(const int* __restrict__ bsum, int nb, int* __restrict__ bexc) {
    __shared__ int s[256];
    int t = threadIdx.x;
    int v = (t < nb) ? bsum[t] : 0;
    s[t] = v;
    __syncthreads();
    for (int off = 1; off < 256; off <<= 1) {
        int tv = (t >= off) ? s[t - off] : 0;
        __syncthreads();
        s[t] += tv;
        __syncthreads();
    }
    bexc[t] = s[t] - v;
}

__global__ void k_scan_add(int* __restrict__ rowptr, const int* __restrict__ bexc) {
    int i = blockIdx.x * 256 + threadIdx.x;
    rowptr[i] += bexc[blockIdx.x];
}

__global__ void k_scatter(const int* __restrict__ ei, int E, const int* __restrict__ rowptr,
                          int* __restrict__ fill, int* __restrict__ csr) {
    int i = blockIdx.x * 256 + threadIdx.x;
    if (i < E) {
        int d = ei[E + i];
        int pos = rowptr[d] + atomicAdd(&fill[d], 1);
        csr[pos] = ei[i];
    }
}

// ---------------- x -> bf16 ----------------
__global__ __launch_bounds__(256) void k_xb(const float* __restrict__ x,
                                            unsigned int* __restrict__ xb, int npairs) {
    int i = blockIdx.x * 256 + threadIdx.x;
    if (i < npairs) {
        float2 v = *(const float2*)(x + (size_t)i * 2);
        xb[i] = (unsigned int)f2bf(v.x) | ((unsigned int)f2bf(v.y) << 16);
    }
}

// ---------------- SAGE mean aggregation: wave per node, bf16 gather ----------------
__global__ __launch_bounds__(256) void k_sage_mean(const int* __restrict__ rowptr,
                                                   const int* __restrict__ csr,
                                                   const unsigned int* __restrict__ xb,
                                                   float* __restrict__ mean, int N) {
    int n = blockIdx.x * 4 + (threadIdx.x >> 6);
    if (n >= N) return;
    int lane = threadIdx.x & 63;
    int e0 = rowptr[n], e1 = rowptr[n + 1];
    float ax = 0.f, ay = 0.f;
    int e = e0;
    for (; e + 1 < e1; e += 2) {
        int s0 = csr[e], s1 = csr[e + 1];
        unsigned int u0 = xb[(size_t)s0 * 64 + lane];
        unsigned int u1 = xb[(size_t)s1 * 64 + lane];
        float2 v0 = bf2_to_f2(u0), v1 = bf2_to_f2(u1);
        ax += v0.x + v1.x; ay += v0.y + v1.y;
    }
    if (e < e1) {
        int s0 = csr[e];
        float2 v0 = bf2_to_f2(xb[(size_t)s0 * 64 + lane]);
        ax += v0.x; ay += v0.y;
    }
    int dg = e1 - e0;
    float inv = 1.0f / (float)(dg > 0 ? dg : 1);
    float2 o; o.x = ax * inv; o.y = ay * inv;
    *(float2*)(mean + (size_t)n * D + lane * 2) = o;
}

// ---------------- h = relu(mean @ W_l + x @ W_r + b_sage); also h -> bf16 ----------------
__global__ __launch_bounds__(256) void k_gemm_h(const float* __restrict__ mean,
                                                const float* __restrict__ x,
                                                const float* __restrict__ Wl,
                                                const float* __restrict__ Wr,
                                                const float* __restrict__ bias,
                                                float* __restrict__ h,
                                                unsigned int* __restrict__ hb, int N) {
    __shared__ float sA[32][128];
    __shared__ float sX[32][128];
    int n0 = blockIdx.x * 32;
    int tid = threadIdx.x;
    for (int i = tid * 4; i < 32 * 128; i += 1024) {
        int r = i >> 7, c = i & 127;
        float4 a = {0, 0, 0, 0}, xx = {0, 0, 0, 0};
        if (n0 + r < N) {
            a = *(const float4*)(mean + (size_t)(n0 + r) * 128 + c);
            xx = *(const float4*)(x + (size_t)(n0 + r) * 128 + c);
        }
        *(float4*)&sA[r][c] = a;
        *(float4*)&sX[r][c] = xx;
    }
    __syncthreads();
    int j0 = (tid & 31) * 4;
    int m0 = (tid >> 5) * 4;
    float acc[4][4] = {};
    #pragma unroll 4
    for (int k = 0; k < 128; k++) {
        float4 w1 = *(const float4*)(Wl + k * 128 + j0);
        float4 w2 = *(const float4*)(Wr + k * 128 + j0);
        #pragma unroll
        for (int m = 0; m < 4; m++) {
            float a = sA[m0 + m][k], b = sX[m0 + m][k];
            acc[m][0] += a * w1.x + b * w2.x;
            acc[m][1] += a * w1.y + b * w2.y;
            acc[m][2] += a * w1.z + b * w2.z;
            acc[m][3] += a * w1.w + b * w2.w;
        }
    }
    float4 bb = *(const float4*)(bias + j0);
    #pragma unroll
    for (int m = 0; m < 4; m++) {
        int n = n0 + m0 + m;
        if (n < N) {
            float4 o;
            o.x = fmaxf(acc[m][0] + bb.x, 0.f);
            o.y = fmaxf(acc[m][1] + bb.y, 0.f);
            o.z = fmaxf(acc[m][2] + bb.z, 0.f);
            o.w = fmaxf(acc[m][3] + bb.w, 0.f);
            *(float4*)(h + (size_t)n * 128 + j0) = o;
            uint2 p;
            p.x = (unsigned int)f2bf(o.x) | ((unsigned int)f2bf(o.y) << 16);
            p.y = (unsigned int)f2bf(o.z) | ((unsigned int)f2bf(o.w) << 16);
            // row = 128 bf16 = 64 uints; elements j0..j0+3 live at uint j0/2, j0/2+1
            *(uint2*)(hb + (size_t)n * 64 + (j0 >> 1)) = p;
        }
    }
}

// ---------------- wsd[k][o] : o<4 -> src att-vec, o>=4 -> dst att-vec ----------------
__global__ void k_wsd(const float* __restrict__ Ws, const float* __restrict__ Wd,
                      const float* __restrict__ atts, const float* __restrict__ attd,
                      float* __restrict__ wsd) {
    int t = blockIdx.x * 256 + threadIdx.x;
    if (t >= 1024) return;
    int k = t >> 3, o = t & 7;
    int hh = o & 3;
    const float* W = (o < 4) ? Ws : Wd;
    const float* att = (o < 4) ? atts : attd;
    float acc = 0.f;
    for (int c = 0; c < 128; c++) acc += W[k * 512 + hh * 128 + c] * att[hh * 128 + c];
    wsd[k * 8 + o] = acc;
}

// ---------------- a_s[N,4], a_d[N,4] = h @ wsd ----------------
__global__ __launch_bounds__(256) void k_asd(const float* __restrict__ h,
                                             const float* __restrict__ wsd,
                                             float* __restrict__ a_s, float* __restrict__ a_d, int N) {
    __shared__ float sH[32][128];
    int n0 = blockIdx.x * 32;
    int tid = threadIdx.x;
    for (int i = tid * 4; i < 32 * 128; i += 1024) {
        int r = i >> 7, c = i & 127;
        float4 v = {0, 0, 0, 0};
        if (n0 + r < N) v = *(const float4*)(h + (size_t)(n0 + r) * 128 + c);
        *(float4*)&sH[r][c] = v;
    }
    __syncthreads();
    int m = tid >> 3, o = tid & 7;
    float acc = 0.f;
    #pragma unroll 4
    for (int k = 0; k < 128; k++) acc += sH[m][k] * wsd[k * 8 + o];
    int n = n0 + m;
    if (n < N) {
        if (o < 4) a_s[n * 4 + o] = acc;
        else       a_d[n * 4 + (o - 4)] = acc;
    }
}

// ---------------- GAT: single-pass softmax-weighted aggregation of h (bf16) ----------------
// agg[n, h*128+c] = (0.25/denom_h) * sum_e exp(leaky(a_s[src]+a_d[n]))_h * h[src][c]
__global__ __launch_bounds__(256) void k_gat_agg(const int* __restrict__ rowptr,
                                                 const int* __restrict__ csr,
                                                 const unsigned int* __restrict__ hb,
                                                 const float* __restrict__ a_s,
                                                 const float* __restrict__ a_d,
                                                 float* __restrict__ agg, int N) {
    int n = blockIdx.x * 4 + (threadIdx.x >> 6);
    if (n >= N) return;
    int lane = threadIdx.x & 63;
    int e0 = rowptr[n], e1 = rowptr[n + 1];
    float4 ad = *(const float4*)(a_d + (size_t)n * 4);
    float d0 = 0.f, d1 = 0.f, d2 = 0.f, d3 = 0.f;
    float2 ac0 = {0, 0}, ac1 = {0, 0}, ac2 = {0, 0}, ac3 = {0, 0};
    int e = e0;
    for (; e + 1 < e1; e += 2) {
        int s0 = csr[e], s1 = csr[e + 1];
        float4 as0 = *(const float4*)(a_s + (size_t)s0 * 4);
        float4 as1 = *(const float4*)(a_s + (size_t)s1 * 4);
        unsigned int u0 = hb[(size_t)s0 * 64 + lane];
        unsigned int u1 = hb[(size_t)s1 * 64 + lane];
        float w00 = __expf(leaky(as0.x + ad.x));
        float w01 = __expf(leaky(as0.y + ad.y));
        float w02 = __expf(leaky(as0.z + ad.z));
        float w03 = __expf(leaky(as0.w + ad.w));
        float w10 = __expf(leaky(as1.x + ad.x));
        float w11 = __expf(leaky(as1.y + ad.y));
        float w12 = __expf(leaky(as1.z + ad.z));
        float w13 = __expf(leaky(as1.w + ad.w));
        d0 += w00 + w10; d1 += w01 + w11; d2 += w02 + w12; d3 += w03 + w13;
        float2 v0 = bf2_to_f2(u0), v1 = bf2_to_f2(u1);
        ac0.x += w00 * v0.x + w10 * v1.x; ac0.y += w00 * v0.y + w10 * v1.y;
        ac1.x += w01 * v0.x + w11 * v1.x; ac1.y += w01 * v0.y + w11 * v1.y;
        ac2.x += w02 * v0.x + w12 * v1.x; ac2.y += w02 * v0.y + w12 * v1.y;
        ac3.x += w03 * v0.x + w13 * v1.x; ac3.y += w03 * v0.y + w13 * v1.y;
    }
    if (e < e1) {
        int s0 = csr[e];
        float4 as0 = *(const float4*)(a_s + (size_t)s0 * 4);
        unsigned int u0 = hb[(size_t)s0 * 64 + lane];
        float w00 = __expf(leaky(as0.x + ad.x));
        float w01 = __expf(leaky(as0.y + ad.y));
        float w02 = __expf(leaky(as0.z + ad.z));
        float w03 = __expf(leaky(as0.w + ad.w));
        d0 += w00; d1 += w01; d2 += w02; d3 += w03;
        float2 v0 = bf2_to_f2(u0);
        ac0.x += w00 * v0.x; ac0.y += w00 * v0.y;
        ac1.x += w01 * v0.x; ac1.y += w01 * v0.y;
        ac2.x += w02 * v0.x; ac2.y += w02 * v0.y;
        ac3.x += w03 * v0.x; ac3.y += w03 * v0.y;
    }
    float i0 = d0 > 0.f ? 0.25f / d0 : 0.f;
    float i1 = d1 > 0.f ? 0.25f / d1 : 0.f;
    float i2 = d2 > 0.f ? 0.25f / d2 : 0.f;
    float i3 = d3 > 0.f ? 0.25f / d3 : 0.f;
    float* row = agg + (size_t)n * 512 + lane * 2;
    float2 o;
    o.x = ac0.x * i0; o.y = ac0.y * i0; *(float2*)(row + 0)   = o;
    o.x = ac1.x * i1; o.y = ac1.y * i1; *(float2*)(row + 128) = o;
    o.x = ac2.x * i2; o.y = ac2.y * i2; *(float2*)(row + 256) = o;
    o.x = ac3.x * i3; o.y = ac3.y * i3; *(float2*)(row + 384) = o;
}

// ---------------- fused: g = relu(sum_h agg_h @ Wsrc_h + bg); out = g @ W_lin + bl ----------------
__global__ __launch_bounds__(256) void k_gemm_gat(const float* __restrict__ agg,
                                                  const float* __restrict__ Ws,
                                                  const float* __restrict__ bg,
                                                  const float* __restrict__ Wlin,
                                                  const float* __restrict__ bl,
                                                  float* __restrict__ out, int N) {
    __shared__ float sA[32][128];
    int n0 = blockIdx.x * 32;
    int tid = threadIdx.x;
    int j0 = (tid & 31) * 4;
    int m0 = (tid >> 5) * 4;
    float acc[4][4] = {};
    for (int kb = 0; kb < 4; kb++) {
        if (kb) __syncthreads();
        for (int i = tid * 4; i < 32 * 128; i += 1024) {
            int r = i >> 7, c = i & 127;
            float4 v = {0, 0, 0, 0};
            if (n0 + r < N) v = *(const float4*)(agg + (size_t)(n0 + r) * 512 + kb * 128 + c);
            *(float4*)&sA[r][c] = v;
        }
        __syncthreads();
        #pragma unroll 4
        for (int k = 0; k < 128; k++) {
            // head kb: out_c += agg[n, kb*128+k] * Wsrc[k, kb*128 + c]
            float4 w = *(const float4*)(Ws + k * 512 + kb * 128 + j0);
            #pragma unroll
            for (int m = 0; m < 4; m++) {
                float a = sA[m0 + m][k];
                acc[m][0] += a * w.x;
                acc[m][1] += a * w.y;
                acc[m][2] += a * w.z;
                acc[m][3] += a * w.w;
            }
        }
    }
    // g = relu(acc + bg) -> sA (reuse)
    __syncthreads();
    float4 bb = *(const float4*)(bg + j0);
    #pragma unroll
    for (int m = 0; m < 4; m++) {
        float4 o;
        o.x = fmaxf(acc[m][0] + bb.x, 0.f);
        o.y = fmaxf(acc[m][1] + bb.y, 0.f);
        o.z = fmaxf(acc[m][2] + bb.z, 0.f);
        o.w = fmaxf(acc[m][3] + bb.w, 0.f);
        *(float4*)&sA[m0 + m][j0] = o;
    }
    __syncthreads();
    // out = g @ Wlin + bl   (32 x 64)
    int j1 = (tid & 15) * 4;
    int m1 = (tid >> 4) * 2;
    float a2[2][4] = {};
    #pragma unroll 4
    for (int k = 0; k < 128; k++) {
        float4 w = *(const float4*)(Wlin + k * 64 + j1);
        #pragma unroll
        for (int m = 0; m < 2; m++) {
            float a = sA[m1 + m][k];
            a2[m][0] += a * w.x;
            a2[m][1] += a * w.y;
            a2[m][2] += a * w.z;
            a2[m][3] += a * w.w;
        }
    }
    float4 b2 = *(const float4*)(bl + j1);
    #pragma unroll
    for (int m = 0; m < 2; m++) {
        int n = n0 + m1 + m;
        if (n < N) {
            float4 o;
            o.x = a2[m][0] + b2.x;
            o.y = a2[m][1] + b2.y;
            o.z = a2[m][2] + b2.z;
            o.w = a2[m][3] + b2.w;
            *(float4*)(out + (size_t)n * 64 + j1) = o;
        }
    }
}

extern "C" void kernel_launch(void* const* d_in, const int* in_sizes, int n_in,
                              void* d_out, int out_size, void* d_ws, size_t ws_size,
                              hipStream_t stream) {
    const float* x    = (const float*)d_in[0];
    const int*   ei   = (const int*)d_in[1];
    const float* Wl   = (const float*)d_in[2];
    const float* Wr   = (const float*)d_in[3];
    const float* bs   = (const float*)d_in[4];
    const float* Wsrc = (const float*)d_in[5];
    const float* Wdst = (const float*)d_in[6];
    const float* atts = (const float*)d_in[7];
    const float* attd = (const float*)d_in[8];
    const float* bg   = (const float*)d_in[9];
    const float* Wlin = (const float*)d_in[10];
    const float* bl   = (const float*)d_in[11];
    int N = in_sizes[0] / D;
    int E = in_sizes[1] / 2;

    // Workspace layout with aliasing:
    //   region0 (N*512*4 bytes) hosts agg; xb (first 12.8MB) and mean (at +16MB)
    //   are dead before agg is written (k_gat_agg runs after k_sage_mean/k_gemm_h).
    char* base = (char*)d_ws;
    float* agg         = (float*)base;
    unsigned int* xb   = (unsigned int*)base;                       // N*64 uints = 12.8 MB
    float* mean        = (float*)(base + (size_t)16 * 1024 * 1024); // 25.6 MB
    char* w = base + (size_t)N * 512 * 4;
    auto alloc = [&](size_t bytes) {
        char* p = w;
        w += (bytes + 255) & ~(size_t)255;
        return p;
    };
    float* hbuf        = (float*)alloc((size_t)N * 128 * 4);
    unsigned int* hb   = (unsigned int*)alloc((size_t)N * 64 * 4);
    float* a_s         = (float*)alloc((size_t)N * 4 * 4);
    float* a_d         = (float*)alloc((size_t)N * 4 * 4);
    float* wsd         = (float*)alloc(1024 * 4);
    int* rowptr        = (int*)alloc((size_t)(N + 512) * 4);
    int* deg           = (int*)alloc((size_t)N * 4);
    int* fill          = (int*)alloc((size_t)N * 4);
    int* bsum          = (int*)alloc(256 * 4);
    int* bexc          = (int*)alloc(256 * 4);
    int* csr           = (int*)alloc((size_t)E * 4);
    (void)ws_size; (void)n_in; (void)out_size;

    hipMemsetAsync(deg, 0, (size_t)N * 4, stream);
    hipMemsetAsync(fill, 0, (size_t)N * 4, stream);

    int nb = (N + 255) / 256;
    k_count<<<(E + 255) / 256, 256, 0, stream>>>(ei, E, deg);
    k_scan_local<<<nb, 256, 0, stream>>>(deg, N, rowptr, bsum);
    k_scan_bsum<<<1, 256, 0, stream>>>(bsum, nb, bexc);
    k_scan_add<<<nb, 256, 0, stream>>>(rowptr, bexc);
    k_scatter<<<(E + 255) / 256, 256, 0, stream>>>(ei, E, rowptr, fill, csr);

    k_xb<<<(N * 64 + 255) / 256, 256, 0, stream>>>(x, xb, N * 64);
    k_sage_mean<<<(N + 3) / 4, 256, 0, stream>>>(rowptr, csr, xb, mean, N);
    k_gemm_h<<<(N + 31) / 32, 256, 0, stream>>>(mean, x, Wl, Wr, bs, hbuf, hb, N);
    k_wsd<<<4, 256, 0, stream>>>(Wsrc, Wdst, atts, attd, wsd);
    k_asd<<<(N + 31) / 32, 256, 0, stream>>>(hbuf, wsd, a_s, a_d, N);
    k_gat_agg<<<(N + 3) / 4, 256, 0, stream>>>(rowptr, csr, hb, a_s, a_d, agg, N);
    k_gemm_gat<<<(N + 31) / 32, 256, 0, stream>>>(agg, Wsrc, bg, Wlin, bl, (float*)d_out, N);
}

// Round 4
// 386.925 us; speedup vs baseline: 1.9684x; 1.4583x over previous
//
#include <hip/hip_runtime.h>

#define D 128
#define HEADS 4

typedef __attribute__((ext_vector_type(8))) short short8;
typedef __attribute__((ext_vector_type(4))) float f32x4;

static __device__ __forceinline__ float leaky(float v) { return v > 0.f ? v : 0.2f * v; }

static __device__ __forceinline__ float2 bf2_to_f2(unsigned int u) {
    float2 r;
    union { unsigned int i; float f; } a, b;
    a.i = (u & 0xffffu) << 16;
    b.i = u & 0xffff0000u;
    r.x = a.f; r.y = b.f;
    return r;
}
static __device__ __forceinline__ unsigned short f2bf(float f) {
    union { float f; unsigned int i; } v; v.f = f;
    unsigned int u = v.i;
    unsigned int r = (u + 0x7fffu + ((u >> 16) & 1u)) >> 16;
    return (unsigned short)r;
}

// ---------------- CSR build ----------------
__global__ void k_count(const int* __restrict__ ei, int E, int* __restrict__ deg) {
    int i = blockIdx.x * 256 + threadIdx.x;
    if (i < E) atomicAdd(&deg[ei[E + i]], 1);
}

__global__ void k_scan_local(const int* __restrict__ deg, int N,
                             int* __restrict__ rowptr, int* __restrict__ bsum) {
    __shared__ int s[256];
    int t = threadIdx.x;
    int i = blockIdx.x * 256 + t;
    int v = (i < N) ? deg[i] : 0;
    s[t] = v;
    __syncthreads();
    for (int off = 1; off < 256; off <<= 1) {
        int tv = (t >= off) ? s[t - off] : 0;
        __syncthreads();
        s[t] += tv;
        __syncthreads();
    }
    rowptr[i] = s[t] - v;  // exclusive
    if (t == 255) bsum[blockIdx.x] = s[255];
}

__global__ void k_scan_bsum(const int* __restrict__ bsum, int nb, int* __restrict__ bexc) {
    __shared__ int s[256];
    int t = threadIdx.x;
    int v = (t < nb) ? bsum[t] : 0;
    s[t] = v;
    __syncthreads();
    for (int off = 1; off < 256; off <<= 1) {
        int tv = (t >= off) ? s[t - off] : 0;
        __syncthreads();
        s[t] += tv;
        __syncthreads();
    }
    bexc[t] = s[t] - v;
}

__global__ void k_scan_add(int* __restrict__ rowptr, const int* __restrict__ bexc) {
    int i = blockIdx.x * 256 + threadIdx.x;
    rowptr[i] += bexc[blockIdx.x];
}

__global__ void k_scatter(const int* __restrict__ ei, int E, const int* __restrict__ rowptr,
                          int* __restrict__ fill, int* __restrict__ csr) {
    int i = blockIdx.x * 256 + threadIdx.x;
    if (i < E) {
        int d = ei[E + i];
        int pos = rowptr[d] + atomicAdd(&fill[d], 1);
        csr[pos] = ei[i];
    }
}

// ---------------- x -> bf16 ----------------
__global__ __launch_bounds__(256) void k_xb(const float* __restrict__ x,
                                            unsigned int* __restrict__ xb, int npairs) {
    int i = blockIdx.x * 256 + threadIdx.x;
    if (i < npairs) {
        float2 v = *(const float2*)(x + (size_t)i * 2);
        xb[i] = (unsigned int)f2bf(v.x) | ((unsigned int)f2bf(v.y) << 16);
    }
}

// ---------------- pack all weights into MFMA B-fragment layout, bf16 ----------------
// layout: offset = (((kb*NC + nc)*4 + quad)*16 + n16)*8 + j ; element (k = kb*32+quad*8+j, n = nc*16+n16)
__global__ __launch_bounds__(256) void k_pack_all(const float* __restrict__ Wl, const float* __restrict__ Wr,
                                                  const float* __restrict__ Wsrc, const float* __restrict__ Wlin,
                                                  unsigned short* __restrict__ Bh,
                                                  unsigned short* __restrict__ Bg,
                                                  unsigned short* __restrict__ Bf) {
    int i = blockIdx.x * 256 + threadIdx.x;
    if (i < 32768) {                       // Bh: K=256, NCOL=128 (concat Wl;Wr)
        int idx = i;
        int j = idx & 7, n16 = (idx >> 3) & 15, quad = (idx >> 7) & 3, rest = idx >> 9;
        int nc = rest & 7, kb = rest >> 3;
        int kk = kb * 32 + quad * 8 + j;
        int n = nc * 16 + n16;
        float v = (kk < 128) ? Wl[kk * 128 + n] : Wr[(kk - 128) * 128 + n];
        Bh[idx] = f2bf(v);
    } else if (i < 32768 + 65536) {        // Bg: K=512, NCOL=128 (head-blocked Wsrc)
        int idx = i - 32768;
        int j = idx & 7, n16 = (idx >> 3) & 15, quad = (idx >> 7) & 3, rest = idx >> 9;
        int nc = rest & 7, kb = rest >> 3;
        int kk = kb * 32 + quad * 8 + j;
        int n = nc * 16 + n16;
        float v = Wsrc[(kk & 127) * 512 + (kk >> 7) * 128 + n];
        Bg[idx] = f2bf(v);
    } else if (i < 32768 + 65536 + 8192) { // Bf: K=128, NCOL=64 (Wlin)
        int idx = i - 98304;
        int j = idx & 7, n16 = (idx >> 3) & 15, quad = (idx >> 7) & 3, rest = idx >> 9;
        int nc = rest & 3, kb = rest >> 2;
        int kk = kb * 32 + quad * 8 + j;
        int n = nc * 16 + n16;
        Bf[idx] = f2bf(Wlin[kk * 64 + n]);
    }
}

// ---------------- SAGE mean aggregation: wave per node, bf16 gather, bf16 out ----------------
__global__ __launch_bounds__(256) void k_sage_mean(const int* __restrict__ rowptr,
                                                   const int* __restrict__ csr,
                                                   const unsigned int* __restrict__ xb,
                                                   unsigned int* __restrict__ meanb, int N) {
    int n = blockIdx.x * 4 + (threadIdx.x >> 6);
    if (n >= N) return;
    int lane = threadIdx.x & 63;
    int e0 = rowptr[n], e1 = rowptr[n + 1];
    float ax = 0.f, ay = 0.f;
    int e = e0;
    for (; e + 1 < e1; e += 2) {
        int s0 = csr[e], s1 = csr[e + 1];
        unsigned int u0 = xb[(size_t)s0 * 64 + lane];
        unsigned int u1 = xb[(size_t)s1 * 64 + lane];
        float2 v0 = bf2_to_f2(u0), v1 = bf2_to_f2(u1);
        ax += v0.x + v1.x; ay += v0.y + v1.y;
    }
    if (e < e1) {
        int s0 = csr[e];
        float2 v0 = bf2_to_f2(xb[(size_t)s0 * 64 + lane]);
        ax += v0.x; ay += v0.y;
    }
    int dg = e1 - e0;
    float inv = 1.0f / (float)(dg > 0 ? dg : 1);
    meanb[(size_t)n * 64 + lane] =
        (unsigned int)f2bf(ax * inv) | ((unsigned int)f2bf(ay * inv) << 16);
}

// ---------------- MFMA GEMM, 2-input A (concat along K): hb = relu([mean|x] @ Bh + bs) ----------------
__global__ __launch_bounds__(256) void k_mfma_h(const unsigned short* __restrict__ A0,
                                                const unsigned short* __restrict__ A1,
                                                const unsigned short* __restrict__ Bp,
                                                const float* __restrict__ bias,
                                                unsigned short* __restrict__ outb, int M) {
    const int NC = 8;                       // NCOL = 128, K = 256
    int wave = threadIdx.x >> 6;
    int lane = threadIdx.x & 63;
    int row0 = blockIdx.x * 64 + wave * 16;
    int n16 = lane & 15, quad = lane >> 4;
    int arow = row0 + n16;
    int arowc = arow < M ? arow : 0;
    f32x4 acc[NC];
    #pragma unroll
    for (int i = 0; i < NC; i++) acc[i] = (f32x4){0.f, 0.f, 0.f, 0.f};
    #pragma unroll
    for (int kb = 0; kb < 8; kb++) {
        const unsigned short* ap = (kb < 4)
            ? (A0 + (size_t)arowc * 128 + kb * 32 + quad * 8)
            : (A1 + (size_t)arowc * 128 + (kb - 4) * 32 + quad * 8);
        short8 af = *(const short8*)ap;
        #pragma unroll
        for (int nc = 0; nc < NC; nc++) {
            short8 bf = *(const short8*)(Bp + ((((size_t)(kb * NC + nc) * 4 + quad) * 16 + n16) << 3));
            acc[nc] = __builtin_amdgcn_mfma_f32_16x16x32_bf16(af, bf, acc[nc], 0, 0, 0);
        }
    }
    int orow = row0 + quad * 4;
    #pragma unroll
    for (int r = 0; r < 4; r++) {
        int m = orow + r;
        if (m < M) {
            #pragma unroll
            for (int nc = 0; nc < NC; nc++) {
                int col = nc * 16 + n16;
                float v = fmaxf(acc[nc][r] + bias[col], 0.f);
                outb[(size_t)m * 128 + col] = f2bf(v);
            }
        }
    }
}

// ---------------- generic MFMA GEMM: out = A[M,K]bf16 @ Bp + bias ----------------
template<int K, int NCOL, bool RELU, bool OUTBF>
__global__ __launch_bounds__(256) void k_mfma_gemm(const unsigned short* __restrict__ A,
                                                   const unsigned short* __restrict__ Bp,
                                                   const float* __restrict__ bias,
                                                   void* __restrict__ out, int M) {
    const int NC = NCOL / 16;
    int wave = threadIdx.x >> 6;
    int lane = threadIdx.x & 63;
    int row0 = blockIdx.x * 64 + wave * 16;
    int n16 = lane & 15, quad = lane >> 4;
    int arow = row0 + n16;
    int arowc = arow < M ? arow : 0;
    const unsigned short* ap = A + (size_t)arowc * K + quad * 8;
    f32x4 acc[NC];
    #pragma unroll
    for (int i = 0; i < NC; i++) acc[i] = (f32x4){0.f, 0.f, 0.f, 0.f};
    #pragma unroll
    for (int kb = 0; kb < K / 32; kb++) {
        short8 af = *(const short8*)(ap + kb * 32);
        #pragma unroll
        for (int nc = 0; nc < NC; nc++) {
            short8 bf = *(const short8*)(Bp + ((((size_t)(kb * NC + nc) * 4 + quad) * 16 + n16) << 3));
            acc[nc] = __builtin_amdgcn_mfma_f32_16x16x32_bf16(af, bf, acc[nc], 0, 0, 0);
        }
    }
    int orow = row0 + quad * 4;
    #pragma unroll
    for (int r = 0; r < 4; r++) {
        int m = orow + r;
        if (m < M) {
            #pragma unroll
            for (int nc = 0; nc < NC; nc++) {
                int col = nc * 16 + n16;
                float v = acc[nc][r] + bias[col];
                if (RELU) v = fmaxf(v, 0.f);
                if (OUTBF) ((unsigned short*)out)[(size_t)m * NCOL + col] = f2bf(v);
                else       ((float*)out)[(size_t)m * NCOL + col] = v;
            }
        }
    }
}

// ---------------- wsd[k][o] : o<4 -> src att-vec, o>=4 -> dst att-vec ----------------
__global__ void k_wsd(const float* __restrict__ Ws, const float* __restrict__ Wd,
                      const float* __restrict__ atts, const float* __restrict__ attd,
                      float* __restrict__ wsd) {
    int t = blockIdx.x * 256 + threadIdx.x;
    if (t >= 1024) return;
    int k = t >> 3, o = t & 7;
    int hh = o & 3;
    const float* W = (o < 4) ? Ws : Wd;
    const float* att = (o < 4) ? atts : attd;
    float acc = 0.f;
    for (int c = 0; c < 128; c++) acc += W[k * 512 + hh * 128 + c] * att[hh * 128 + c];
    wsd[k * 8 + o] = acc;
}

// ---------------- a_s[N,4], a_d[N,4] = h(bf16) @ wsd ----------------
__global__ __launch_bounds__(256) void k_asd(const unsigned int* __restrict__ hb_u,
                                             const float* __restrict__ wsd,
                                             float* __restrict__ a_s, float* __restrict__ a_d, int N) {
    __shared__ unsigned int sH[32][68];  // 68: 16B-aligned rows, conflict-free stride
    int n0 = blockIdx.x * 32;
    int tid = threadIdx.x;
    {
        int i = tid * 8;                 // 256 threads x 8 uints = 2048 = 32*64
        int r = i >> 6, c = i & 63;
        uint4 v0 = {0, 0, 0, 0}, v1 = {0, 0, 0, 0};
        if (n0 + r < N) {
            v0 = *(const uint4*)(hb_u + (size_t)(n0 + r) * 64 + c);
            v1 = *(const uint4*)(hb_u + (size_t)(n0 + r) * 64 + c + 4);
        }
        *(uint4*)&sH[r][c] = v0;
        *(uint4*)&sH[r][c + 4] = v1;
    }
    __syncthreads();
    int m = tid >> 3, o = tid & 7;
    float acc = 0.f;
    #pragma unroll 4
    for (int ku = 0; ku < 64; ku++) {
        float2 v = bf2_to_f2(sH[m][ku]);
        acc += v.x * wsd[(2 * ku) * 8 + o] + v.y * wsd[(2 * ku + 1) * 8 + o];
    }
    int n = n0 + m;
    if (n < N) {
        if (o < 4) a_s[n * 4 + o] = acc;
        else       a_d[n * 4 + (o - 4)] = acc;
    }
}

// ---------------- GAT: single-pass softmax-weighted aggregation of h (bf16), bf16 out ----------------
__global__ __launch_bounds__(256) void k_gat_agg(const int* __restrict__ rowptr,
                                                 const int* __restrict__ csr,
                                                 const unsigned int* __restrict__ hb,
                                                 const float* __restrict__ a_s,
                                                 const float* __restrict__ a_d,
                                                 unsigned int* __restrict__ aggb, int N) {
    int n = blockIdx.x * 4 + (threadIdx.x >> 6);
    if (n >= N) return;
    int lane = threadIdx.x & 63;
    int e0 = rowptr[n], e1 = rowptr[n + 1];
    float4 ad = *(const float4*)(a_d + (size_t)n * 4);
    float d0 = 0.f, d1 = 0.f, d2 = 0.f, d3 = 0.f;
    float2 ac0 = {0, 0}, ac1 = {0, 0}, ac2 = {0, 0}, ac3 = {0, 0};
    int e = e0;
    for (; e + 1 < e1; e += 2) {
        int s0 = csr[e], s1 = csr[e + 1];
        float4 as0 = *(const float4*)(a_s + (size_t)s0 * 4);
        float4 as1 = *(const float4*)(a_s + (size_t)s1 * 4);
        unsigned int u0 = hb[(size_t)s0 * 64 + lane];
        unsigned int u1 = hb[(size_t)s1 * 64 + lane];
        float w00 = __expf(leaky(as0.x + ad.x));
        float w01 = __expf(leaky(as0.y + ad.y));
        float w02 = __expf(leaky(as0.z + ad.z));
        float w03 = __expf(leaky(as0.w + ad.w));
        float w10 = __expf(leaky(as1.x + ad.x));
        float w11 = __expf(leaky(as1.y + ad.y));
        float w12 = __expf(leaky(as1.z + ad.z));
        float w13 = __expf(leaky(as1.w + ad.w));
        d0 += w00 + w10; d1 += w01 + w11; d2 += w02 + w12; d3 += w03 + w13;
        float2 v0 = bf2_to_f2(u0), v1 = bf2_to_f2(u1);
        ac0.x += w00 * v0.x + w10 * v1.x; ac0.y += w00 * v0.y + w10 * v1.y;
        ac1.x += w01 * v0.x + w11 * v1.x; ac1.y += w01 * v0.y + w11 * v1.y;
        ac2.x += w02 * v0.x + w12 * v1.x; ac2.y += w02 * v0.y + w12 * v1.y;
        ac3.x += w03 * v0.x + w13 * v1.x; ac3.y += w03 * v0.y + w13 * v1.y;
    }
    if (e < e1) {
        int s0 = csr[e];
        float4 as0 = *(const float4*)(a_s + (size_t)s0 * 4);
        unsigned int u0 = hb[(size_t)s0 * 64 + lane];
        float w00 = __expf(leaky(as0.x + ad.x));
        float w01 = __expf(leaky(as0.y + ad.y));
        float w02 = __expf(leaky(as0.z + ad.z));
        float w03 = __expf(leaky(as0.w + ad.w));
        d0 += w00; d1 += w01; d2 += w02; d3 += w03;
        float2 v0 = bf2_to_f2(u0);
        ac0.x += w00 * v0.x; ac0.y += w00 * v0.y;
        ac1.x += w01 * v0.x; ac1.y += w01 * v0.y;
        ac2.x += w02 * v0.x; ac2.y += w02 * v0.y;
        ac3.x += w03 * v0.x; ac3.y += w03 * v0.y;
    }
    float i0 = d0 > 0.f ? 0.25f / d0 : 0.f;
    float i1 = d1 > 0.f ? 0.25f / d1 : 0.f;
    float i2 = d2 > 0.f ? 0.25f / d2 : 0.f;
    float i3 = d3 > 0.f ? 0.25f / d3 : 0.f;
    unsigned int* rowu = aggb + (size_t)n * 256 + lane;
    rowu[0]   = (unsigned int)f2bf(ac0.x * i0) | ((unsigned int)f2bf(ac0.y * i0) << 16);
    rowu[64]  = (unsigned int)f2bf(ac1.x * i1) | ((unsigned int)f2bf(ac1.y * i1) << 16);
    rowu[128] = (unsigned int)f2bf(ac2.x * i2) | ((unsigned int)f2bf(ac2.y * i2) << 16);
    rowu[192] = (unsigned int)f2bf(ac3.x * i3) | ((unsigned int)f2bf(ac3.y * i3) << 16);
}

extern "C" void kernel_launch(void* const* d_in, const int* in_sizes, int n_in,
                              void* d_out, int out_size, void* d_ws, size_t ws_size,
                              hipStream_t stream) {
    const float* x    = (const float*)d_in[0];
    const int*   ei   = (const int*)d_in[1];
    const float* Wl   = (const float*)d_in[2];
    const float* Wr   = (const float*)d_in[3];
    const float* bs   = (const float*)d_in[4];
    const float* Wsrc = (const float*)d_in[5];
    const float* Wdst = (const float*)d_in[6];
    const float* atts = (const float*)d_in[7];
    const float* attd = (const float*)d_in[8];
    const float* bg   = (const float*)d_in[9];
    const float* Wlin = (const float*)d_in[10];
    const float* bl   = (const float*)d_in[11];
    int N = in_sizes[0] / D;
    int E = in_sizes[1] / 2;

    char* w = (char*)d_ws;
    auto alloc = [&](size_t bytes) {
        char* p = w;
        w += (bytes + 255) & ~(size_t)255;
        return p;
    };
    unsigned int* xb     = (unsigned int*)alloc((size_t)N * 256);   // [N,128] bf16
    unsigned int* meanb  = (unsigned int*)alloc((size_t)N * 256);   // [N,128] bf16
    unsigned int* hb     = (unsigned int*)alloc((size_t)N * 256);   // [N,128] bf16
    unsigned int* aggb   = (unsigned int*)alloc((size_t)N * 1024);  // [N,512] bf16
    unsigned int* gb     = (unsigned int*)alloc((size_t)N * 256);   // [N,128] bf16
    unsigned short* Bh   = (unsigned short*)alloc(65536 * 2);
    unsigned short* Bg   = (unsigned short*)alloc(65536 * 2);
    unsigned short* Bf   = (unsigned short*)alloc(8192 * 2);
    float* a_s           = (float*)alloc((size_t)N * 16);
    float* a_d           = (float*)alloc((size_t)N * 16);
    float* wsd           = (float*)alloc(1024 * 4);
    int* rowptr          = (int*)alloc((size_t)(N + 512) * 4);
    int* deg             = (int*)alloc((size_t)N * 4);
    int* fill            = (int*)alloc((size_t)N * 4);
    int* bsum            = (int*)alloc(256 * 4);
    int* bexc            = (int*)alloc(256 * 4);
    int* csr             = (int*)alloc((size_t)E * 4);
    (void)ws_size; (void)n_in; (void)out_size;

    hipMemsetAsync(deg, 0, (size_t)N * 4, stream);
    hipMemsetAsync(fill, 0, (size_t)N * 4, stream);

    int nb = (N + 255) / 256;
    k_count<<<(E + 255) / 256, 256, 0, stream>>>(ei, E, deg);
    k_scan_local<<<nb, 256, 0, stream>>>(deg, N, rowptr, bsum);
    k_scan_bsum<<<1, 256, 0, stream>>>(bsum, nb, bexc);
    k_scan_add<<<nb, 256, 0, stream>>>(rowptr, bexc);
    k_scatter<<<(E + 255) / 256, 256, 0, stream>>>(ei, E, rowptr, fill, csr);

    k_xb<<<(N * 64 + 255) / 256, 256, 0, stream>>>(x, xb, N * 64);
    k_pack_all<<<(106496 + 255) / 256, 256, 0, stream>>>(Wl, Wr, Wsrc, Wlin, Bh, Bg, Bf);
    k_sage_mean<<<(N + 3) / 4, 256, 0, stream>>>(rowptr, csr, xb, meanb, N);
    k_mfma_h<<<(N + 63) / 64, 256, 0, stream>>>((const unsigned short*)meanb,
                                                (const unsigned short*)xb, Bh, bs,
                                                (unsigned short*)hb, N);
    k_wsd<<<4, 256, 0, stream>>>(Wsrc, Wdst, atts, attd, wsd);
    k_asd<<<(N + 31) / 32, 256, 0, stream>>>(hb, wsd, a_s, a_d, N);
    k_gat_agg<<<(N + 3) / 4, 256, 0, stream>>>(rowptr, csr, hb, a_s, a_d, aggb, N);
    k_mfma_gemm<512, 128, true, true><<<(N + 63) / 64, 256, 0, stream>>>(
        (const unsigned short*)aggb, Bg, bg, (void*)gb, N);
    k_mfma_gemm<128, 64, false, false><<<(N + 63) / 64, 256, 0, stream>>>(
        (const unsigned short*)gb, Bf, bl, d_out, N);
}

// Round 5
// 379.231 us; speedup vs baseline: 2.0084x; 1.0203x over previous
//
#include <hip/hip_runtime.h>

#define D 128
#define HEADS 4

typedef __attribute__((ext_vector_type(8))) short short8;
typedef __attribute__((ext_vector_type(4))) float f32x4;

static __device__ __forceinline__ float leaky(float v) { return v > 0.f ? v : 0.2f * v; }

static __device__ __forceinline__ float2 bf2_to_f2(unsigned int u) {
    float2 r;
    union { unsigned int i; float f; } a, b;
    a.i = (u & 0xffffu) << 16;
    b.i = u & 0xffff0000u;
    r.x = a.f; r.y = b.f;
    return r;
}
static __device__ __forceinline__ unsigned short f2bf(float f) {
    union { float f; unsigned int i; } v; v.f = f;
    unsigned int u = v.i;
    unsigned int r = (u + 0x7fffu + ((u >> 16) & 1u)) >> 16;
    return (unsigned short)r;
}

// ---------------- CSR build ----------------
__global__ void k_count(const int* __restrict__ ei, int E, int* __restrict__ deg) {
    int i = blockIdx.x * 256 + threadIdx.x;
    if (i < E) atomicAdd(&deg[ei[E + i]], 1);
}

__global__ void k_scan_local(const int* __restrict__ deg, int N,
                             int* __restrict__ rowptr, int* __restrict__ bsum) {
    __shared__ int s[256];
    int t = threadIdx.x;
    int i = blockIdx.x * 256 + t;
    int v = (i < N) ? deg[i] : 0;
    s[t] = v;
    __syncthreads();
    for (int off = 1; off < 256; off <<= 1) {
        int tv = (t >= off) ? s[t - off] : 0;
        __syncthreads();
        s[t] += tv;
        __syncthreads();
    }
    rowptr[i] = s[t] - v;  // exclusive
    if (t == 255) bsum[blockIdx.x] = s[255];
}

__global__ void k_scan_bsum(const int* __restrict__ bsum, int nb, int* __restrict__ bexc) {
    __shared__ int s[256];
    int t = threadIdx.x;
    int v = (t < nb) ? bsum[t] : 0;
    s[t] = v;
    __syncthreads();
    for (int off = 1; off < 256; off <<= 1) {
        int tv = (t >= off) ? s[t - off] : 0;
        __syncthreads();
        s[t] += tv;
        __syncthreads();
    }
    bexc[t] = s[t] - v;
}

__global__ void k_scan_add(int* __restrict__ rowptr, const int* __restrict__ bexc) {
    int i = blockIdx.x * 256 + threadIdx.x;
    rowptr[i] += bexc[blockIdx.x];
}

__global__ void k_scatter(const int* __restrict__ ei, int E, const int* __restrict__ rowptr,
                          int* __restrict__ fill, int* __restrict__ csr,
                          int* __restrict__ dstc) {
    int i = blockIdx.x * 256 + threadIdx.x;
    if (i < E) {
        int d = ei[E + i];
        int pos = rowptr[d] + atomicAdd(&fill[d], 1);
        csr[pos] = ei[i];
        dstc[pos] = d;
    }
}

// ---------------- x -> bf16 ----------------
__global__ __launch_bounds__(256) void k_xb(const float* __restrict__ x,
                                            unsigned int* __restrict__ xb, int npairs) {
    int i = blockIdx.x * 256 + threadIdx.x;
    if (i < npairs) {
        float2 v = *(const float2*)(x + (size_t)i * 2);
        xb[i] = (unsigned int)f2bf(v.x) | ((unsigned int)f2bf(v.y) << 16);
    }
}

// ---------------- prep: pack weights to MFMA B-frag layout + wsd attention vectors ----------------
// B layout: offset = (((kb*NC + nc)*4 + quad)*16 + n16)*8 + j ; element (k = kb*32+quad*8+j, n = nc*16+n16)
__global__ __launch_bounds__(256) void k_prep(const float* __restrict__ Wl, const float* __restrict__ Wr,
                                              const float* __restrict__ Wsrc, const float* __restrict__ Wlin,
                                              const float* __restrict__ Wdst,
                                              const float* __restrict__ atts, const float* __restrict__ attd,
                                              unsigned short* __restrict__ Bh,
                                              unsigned short* __restrict__ Bg,
                                              unsigned short* __restrict__ Bf,
                                              float* __restrict__ wsd) {
    int i = blockIdx.x * 256 + threadIdx.x;
    if (i < 32768) {                       // Bh: K=256, NCOL=128 (concat Wl;Wr)
        int idx = i;
        int j = idx & 7, n16 = (idx >> 3) & 15, quad = (idx >> 7) & 3, rest = idx >> 9;
        int nc = rest & 7, kb = rest >> 3;
        int kk = kb * 32 + quad * 8 + j;
        int n = nc * 16 + n16;
        float v = (kk < 128) ? Wl[kk * 128 + n] : Wr[(kk - 128) * 128 + n];
        Bh[idx] = f2bf(v);
    } else if (i < 32768 + 65536) {        // Bg: K=512, NCOL=128 (head-blocked Wsrc)
        int idx = i - 32768;
        int j = idx & 7, n16 = (idx >> 3) & 15, quad = (idx >> 7) & 3, rest = idx >> 9;
        int nc = rest & 7, kb = rest >> 3;
        int kk = kb * 32 + quad * 8 + j;
        int n = nc * 16 + n16;
        float v = Wsrc[(kk & 127) * 512 + (kk >> 7) * 128 + n];
        Bg[idx] = f2bf(v);
    } else if (i < 32768 + 65536 + 8192) { // Bf: K=128, NCOL=64 (Wlin)
        int idx = i - 98304;
        int j = idx & 7, n16 = (idx >> 3) & 15, quad = (idx >> 7) & 3, rest = idx >> 9;
        int nc = rest & 3, kb = rest >> 2;
        int kk = kb * 32 + quad * 8 + j;
        int n = nc * 16 + n16;
        Bf[idx] = f2bf(Wlin[kk * 64 + n]);
    } else if (i < 32768 + 65536 + 8192 + 1024) { // wsd
        int t = i - 106496;
        int k = t >> 3, o = t & 7;
        int hh = o & 3;
        const float* W = (o < 4) ? Wsrc : Wdst;
        const float* att = (o < 4) ? atts : attd;
        float acc = 0.f;
        for (int c = 0; c < 128; c++) acc += W[k * 512 + hh * 128 + c] * att[hh * 128 + c];
        wsd[k * 8 + o] = acc;
    }
}

// ---------------- SAGE mean aggregation: wave per node, bf16 gather, bf16 out ----------------
__global__ __launch_bounds__(256) void k_sage_mean(const int* __restrict__ rowptr,
                                                   const int* __restrict__ csr,
                                                   const unsigned int* __restrict__ xb,
                                                   unsigned int* __restrict__ meanb, int N) {
    int n = blockIdx.x * 4 + (threadIdx.x >> 6);
    if (n >= N) return;
    int lane = threadIdx.x & 63;
    int e0 = rowptr[n], e1 = rowptr[n + 1];
    float ax = 0.f, ay = 0.f;
    int e = e0;
    for (; e + 1 < e1; e += 2) {
        int s0 = csr[e], s1 = csr[e + 1];
        unsigned int u0 = xb[(size_t)s0 * 64 + lane];
        unsigned int u1 = xb[(size_t)s1 * 64 + lane];
        float2 v0 = bf2_to_f2(u0), v1 = bf2_to_f2(u1);
        ax += v0.x + v1.x; ay += v0.y + v1.y;
    }
    if (e < e1) {
        int s0 = csr[e];
        float2 v0 = bf2_to_f2(xb[(size_t)s0 * 64 + lane]);
        ax += v0.x; ay += v0.y;
    }
    int dg = e1 - e0;
    float inv = 1.0f / (float)(dg > 0 ? dg : 1);
    meanb[(size_t)n * 64 + lane] =
        (unsigned int)f2bf(ax * inv) | ((unsigned int)f2bf(ay * inv) << 16);
}

// ---------------- MFMA GEMM, 2-input A (concat along K): hb = relu([mean|x] @ Bh + bs) ----------------
__global__ __launch_bounds__(256) void k_mfma_h(const unsigned short* __restrict__ A0,
                                                const unsigned short* __restrict__ A1,
                                                const unsigned short* __restrict__ Bp,
                                                const float* __restrict__ bias,
                                                unsigned short* __restrict__ outb, int M) {
    const int NC = 8;                       // NCOL = 128, K = 256
    int wave = threadIdx.x >> 6;
    int lane = threadIdx.x & 63;
    int row0 = blockIdx.x * 64 + wave * 16;
    int n16 = lane & 15, quad = lane >> 4;
    int arow = row0 + n16;
    int arowc = arow < M ? arow : 0;
    f32x4 acc[NC];
    #pragma unroll
    for (int i = 0; i < NC; i++) acc[i] = (f32x4){0.f, 0.f, 0.f, 0.f};
    #pragma unroll
    for (int kb = 0; kb < 8; kb++) {
        const unsigned short* ap = (kb < 4)
            ? (A0 + (size_t)arowc * 128 + kb * 32 + quad * 8)
            : (A1 + (size_t)arowc * 128 + (kb - 4) * 32 + quad * 8);
        short8 af = *(const short8*)ap;
        #pragma unroll
        for (int nc = 0; nc < NC; nc++) {
            short8 bf = *(const short8*)(Bp + ((((size_t)(kb * NC + nc) * 4 + quad) * 16 + n16) << 3));
            acc[nc] = __builtin_amdgcn_mfma_f32_16x16x32_bf16(af, bf, acc[nc], 0, 0, 0);
        }
    }
    int orow = row0 + quad * 4;
    #pragma unroll
    for (int r = 0; r < 4; r++) {
        int m = orow + r;
        if (m < M) {
            #pragma unroll
            for (int nc = 0; nc < NC; nc++) {
                int col = nc * 16 + n16;
                float v = fmaxf(acc[nc][r] + bias[col], 0.f);
                outb[(size_t)m * 128 + col] = f2bf(v);
            }
        }
    }
}

// ---------------- a_s[N,4], a_d[N,4] = h(bf16) @ wsd ----------------
__global__ __launch_bounds__(256) void k_asd(const unsigned int* __restrict__ hb_u,
                                             const float* __restrict__ wsd,
                                             float* __restrict__ a_s, float* __restrict__ a_d, int N) {
    __shared__ unsigned int sH[32][68];
    int n0 = blockIdx.x * 32;
    int tid = threadIdx.x;
    {
        int i = tid * 8;
        int r = i >> 6, c = i & 63;
        uint4 v0 = {0, 0, 0, 0}, v1 = {0, 0, 0, 0};
        if (n0 + r < N) {
            v0 = *(const uint4*)(hb_u + (size_t)(n0 + r) * 64 + c);
            v1 = *(const uint4*)(hb_u + (size_t)(n0 + r) * 64 + c + 4);
        }
        *(uint4*)&sH[r][c] = v0;
        *(uint4*)&sH[r][c + 4] = v1;
    }
    __syncthreads();
    int m = tid >> 3, o = tid & 7;
    float acc = 0.f;
    #pragma unroll 4
    for (int ku = 0; ku < 64; ku++) {
        float2 v = bf2_to_f2(sH[m][ku]);
        acc += v.x * wsd[(2 * ku) * 8 + o] + v.y * wsd[(2 * ku + 1) * 8 + o];
    }
    int n = n0 + m;
    if (n < N) {
        if (o < 4) a_s[n * 4 + o] = acc;
        else       a_d[n * 4 + (o - 4)] = acc;
    }
}

// ---------------- per-edge exp weights (balanced, coalesced) ----------------
__global__ __launch_bounds__(256) void k_edgew(const int* __restrict__ csr,
                                               const int* __restrict__ dstc,
                                               const float* __restrict__ a_s,
                                               const float* __restrict__ a_d,
                                               float4* __restrict__ wexp, int E) {
    int i = blockIdx.x * 256 + threadIdx.x;
    if (i < E) {
        int s = csr[i], d = dstc[i];
        float4 as = *(const float4*)(a_s + (size_t)s * 4);
        float4 ad = *(const float4*)(a_d + (size_t)d * 4);
        float4 w;
        w.x = __expf(leaky(as.x + ad.x));
        w.y = __expf(leaky(as.y + ad.y));
        w.z = __expf(leaky(as.z + ad.z));
        w.w = __expf(leaky(as.w + ad.w));
        wexp[i] = w;
    }
}

// ---------------- GAT: weighted aggregation with precomputed weights, bf16 out ----------------
__global__ __launch_bounds__(256) void k_gat_agg(const int* __restrict__ rowptr,
                                                 const int* __restrict__ csr,
                                                 const unsigned int* __restrict__ hb,
                                                 const float4* __restrict__ wexp,
                                                 unsigned int* __restrict__ aggb, int N) {
    int n = blockIdx.x * 4 + (threadIdx.x >> 6);
    if (n >= N) return;
    int lane = threadIdx.x & 63;
    int e0 = rowptr[n], e1 = rowptr[n + 1];
    float d0 = 0.f, d1 = 0.f, d2 = 0.f, d3 = 0.f;
    float2 ac0 = {0, 0}, ac1 = {0, 0}, ac2 = {0, 0}, ac3 = {0, 0};
    int e = e0;
    for (; e + 1 < e1; e += 2) {
        int s0 = csr[e], s1 = csr[e + 1];
        float4 w0 = wexp[e], w1 = wexp[e + 1];
        unsigned int u0 = hb[(size_t)s0 * 64 + lane];
        unsigned int u1 = hb[(size_t)s1 * 64 + lane];
        d0 += w0.x + w1.x; d1 += w0.y + w1.y; d2 += w0.z + w1.z; d3 += w0.w + w1.w;
        float2 v0 = bf2_to_f2(u0), v1 = bf2_to_f2(u1);
        ac0.x += w0.x * v0.x + w1.x * v1.x; ac0.y += w0.x * v0.y + w1.x * v1.y;
        ac1.x += w0.y * v0.x + w1.y * v1.x; ac1.y += w0.y * v0.y + w1.y * v1.y;
        ac2.x += w0.z * v0.x + w1.z * v1.x; ac2.y += w0.z * v0.y + w1.z * v1.y;
        ac3.x += w0.w * v0.x + w1.w * v1.x; ac3.y += w0.w * v0.y + w1.w * v1.y;
    }
    if (e < e1) {
        int s0 = csr[e];
        float4 w0 = wexp[e];
        unsigned int u0 = hb[(size_t)s0 * 64 + lane];
        d0 += w0.x; d1 += w0.y; d2 += w0.z; d3 += w0.w;
        float2 v0 = bf2_to_f2(u0);
        ac0.x += w0.x * v0.x; ac0.y += w0.x * v0.y;
        ac1.x += w0.y * v0.x; ac1.y += w0.y * v0.y;
        ac2.x += w0.z * v0.x; ac2.y += w0.z * v0.y;
        ac3.x += w0.w * v0.x; ac3.y += w0.w * v0.y;
    }
    float i0 = d0 > 0.f ? 0.25f / d0 : 0.f;
    float i1 = d1 > 0.f ? 0.25f / d1 : 0.f;
    float i2 = d2 > 0.f ? 0.25f / d2 : 0.f;
    float i3 = d3 > 0.f ? 0.25f / d3 : 0.f;
    unsigned int* rowu = aggb + (size_t)n * 256 + lane;
    rowu[0]   = (unsigned int)f2bf(ac0.x * i0) | ((unsigned int)f2bf(ac0.y * i0) << 16);
    rowu[64]  = (unsigned int)f2bf(ac1.x * i1) | ((unsigned int)f2bf(ac1.y * i1) << 16);
    rowu[128] = (unsigned int)f2bf(ac2.x * i2) | ((unsigned int)f2bf(ac2.y * i2) << 16);
    rowu[192] = (unsigned int)f2bf(ac3.x * i3) | ((unsigned int)f2bf(ac3.y * i3) << 16);
}

// ---------------- fused tail: g = relu(aggb @ Bg + bg); out = g @ Bf + bl ----------------
__global__ __launch_bounds__(256) void k_mfma_tail(const unsigned short* __restrict__ aggb,
                                                   const unsigned short* __restrict__ Bg,
                                                   const float* __restrict__ bg,
                                                   const unsigned short* __restrict__ Bf,
                                                   const float* __restrict__ bl,
                                                   float* __restrict__ out, int M) {
    __shared__ unsigned short sG[64][136];   // +8-short pad -> only 2-way (free) LDS aliasing
    int wave = threadIdx.x >> 6;
    int lane = threadIdx.x & 63;
    int row0 = blockIdx.x * 64 + wave * 16;
    int n16 = lane & 15, quad = lane >> 4;
    // ---- stage 1: K=512, NCOL=128 ----
    {
        int arow = row0 + n16;
        int arowc = arow < M ? arow : 0;
        const unsigned short* ap = aggb + (size_t)arowc * 512 + quad * 8;
        f32x4 acc[8];
        #pragma unroll
        for (int i = 0; i < 8; i++) acc[i] = (f32x4){0.f, 0.f, 0.f, 0.f};
        #pragma unroll
        for (int kb = 0; kb < 16; kb++) {
            short8 af = *(const short8*)(ap + kb * 32);
            #pragma unroll
            for (int nc = 0; nc < 8; nc++) {
                short8 bf = *(const short8*)(Bg + ((((size_t)(kb * 8 + nc) * 4 + quad) * 16 + n16) << 3));
                acc[nc] = __builtin_amdgcn_mfma_f32_16x16x32_bf16(af, bf, acc[nc], 0, 0, 0);
            }
        }
        int lrow = wave * 16 + quad * 4;
        #pragma unroll
        for (int r = 0; r < 4; r++) {
            #pragma unroll
            for (int nc = 0; nc < 8; nc++) {
                int col = nc * 16 + n16;
                sG[lrow + r][col] = f2bf(fmaxf(acc[nc][r] + bg[col], 0.f));
            }
        }
    }
    __syncthreads();
    // ---- stage 2: K=128, NCOL=64 from LDS ----
    {
        f32x4 acc[4];
        #pragma unroll
        for (int i = 0; i < 4; i++) acc[i] = (f32x4){0.f, 0.f, 0.f, 0.f};
        #pragma unroll
        for (int kb = 0; kb < 4; kb++) {
            short8 af = *(const short8*)&sG[wave * 16 + n16][kb * 32 + quad * 8];
            #pragma unroll
            for (int nc = 0; nc < 4; nc++) {
                short8 bf = *(const short8*)(Bf + ((((size_t)(kb * 4 + nc) * 4 + quad) * 16 + n16) << 3));
                acc[nc] = __builtin_amdgcn_mfma_f32_16x16x32_bf16(af, bf, acc[nc], 0, 0, 0);
            }
        }
        int orow = row0 + quad * 4;
        #pragma unroll
        for (int r = 0; r < 4; r++) {
            int m = orow + r;
            if (m < M) {
                #pragma unroll
                for (int nc = 0; nc < 4; nc++) {
                    int col = nc * 16 + n16;
                    out[(size_t)m * 64 + col] = acc[nc][r] + bl[col];
                }
            }
        }
    }
}

extern "C" void kernel_launch(void* const* d_in, const int* in_sizes, int n_in,
                              void* d_out, int out_size, void* d_ws, size_t ws_size,
                              hipStream_t stream) {
    const float* x    = (const float*)d_in[0];
    const int*   ei   = (const int*)d_in[1];
    const float* Wl   = (const float*)d_in[2];
    const float* Wr   = (const float*)d_in[3];
    const float* bs   = (const float*)d_in[4];
    const float* Wsrc = (const float*)d_in[5];
    const float* Wdst = (const float*)d_in[6];
    const float* atts = (const float*)d_in[7];
    const float* attd = (const float*)d_in[8];
    const float* bg   = (const float*)d_in[9];
    const float* Wlin = (const float*)d_in[10];
    const float* bl   = (const float*)d_in[11];
    int N = in_sizes[0] / D;
    int E = in_sizes[1] / 2;

    char* w = (char*)d_ws;
    auto alloc = [&](size_t bytes) {
        char* p = w;
        w += (bytes + 255) & ~(size_t)255;
        return p;
    };
    unsigned int* xb     = (unsigned int*)alloc((size_t)N * 256);   // [N,128] bf16
    unsigned int* meanb  = (unsigned int*)alloc((size_t)N * 256);   // [N,128] bf16
    unsigned int* hb     = (unsigned int*)alloc((size_t)N * 256);   // [N,128] bf16
    unsigned int* aggb   = (unsigned int*)alloc((size_t)N * 1024);  // [N,512] bf16
    float4* wexp         = (float4*)alloc((size_t)E * 16);          // [E,4] fp32
    unsigned short* Bh   = (unsigned short*)alloc(65536 * 2);
    unsigned short* Bg   = (unsigned short*)alloc(65536 * 2);
    unsigned short* Bf   = (unsigned short*)alloc(8192 * 2);
    float* a_s           = (float*)alloc((size_t)N * 16);
    float* a_d           = (float*)alloc((size_t)N * 16);
    float* wsd           = (float*)alloc(1024 * 4);
    int* rowptr          = (int*)alloc((size_t)(N + 512) * 4);
    size_t degbytes      = (((size_t)N * 4) + 255) & ~(size_t)255;
    int* deg             = (int*)alloc(2 * degbytes);               // deg + fill contiguous
    int* fill            = (int*)((char*)deg + degbytes);
    int* bsum            = (int*)alloc(256 * 4);
    int* bexc            = (int*)alloc(256 * 4);
    int* csr             = (int*)alloc((size_t)E * 4);
    int* dstc            = (int*)alloc((size_t)E * 4);
    (void)ws_size; (void)n_in; (void)out_size;

    hipMemsetAsync(deg, 0, 2 * degbytes, stream);

    int nb = (N + 255) / 256;
    k_count<<<(E + 255) / 256, 256, 0, stream>>>(ei, E, deg);
    k_scan_local<<<nb, 256, 0, stream>>>(deg, N, rowptr, bsum);
    k_scan_bsum<<<1, 256, 0, stream>>>(bsum, nb, bexc);
    k_scan_add<<<nb, 256, 0, stream>>>(rowptr, bexc);
    k_scatter<<<(E + 255) / 256, 256, 0, stream>>>(ei, E, rowptr, fill, csr, dstc);

    k_xb<<<(N * 64 + 255) / 256, 256, 0, stream>>>(x, xb, N * 64);
    k_prep<<<(107520 + 255) / 256, 256, 0, stream>>>(Wl, Wr, Wsrc, Wlin, Wdst, atts, attd,
                                                     Bh, Bg, Bf, wsd);
    k_sage_mean<<<(N + 3) / 4, 256, 0, stream>>>(rowptr, csr, xb, meanb, N);
    k_mfma_h<<<(N + 63) / 64, 256, 0, stream>>>((const unsigned short*)meanb,
                                                (const unsigned short*)xb, Bh, bs,
                                                (unsigned short*)hb, N);
    k_asd<<<(N + 31) / 32, 256, 0, stream>>>(hb, wsd, a_s, a_d, N);
    k_edgew<<<(E + 255) / 256, 256, 0, stream>>>(csr, dstc, a_s, a_d, wexp, E);
    k_gat_agg<<<(N + 3) / 4, 256, 0, stream>>>(rowptr, csr, hb, wexp, aggb, N);
    k_mfma_tail<<<(N + 63) / 64, 256, 0, stream>>>((const unsigned short*)aggb, Bg, bg,
                                                   Bf, bl, (float*)d_out, N);
}